// Round 6
// baseline (141.167 us; speedup 1.0000x reference)
//
#include <hip/hip_runtime.h>

#define FEAT   256
#define K2     512      // 2*FEAT
#define NNODES 100000
#define BATCH  50000
#define NS     10
#define EMBED  256
#define BN     32
#define NBLK   ((BATCH + BN - 1) / BN)   // 1563

typedef __attribute__((ext_vector_type(8))) __bf16         bf16x8;
typedef __attribute__((ext_vector_type(8))) unsigned short ushort8;
typedef __attribute__((ext_vector_type(4))) float          f32x4;

static __device__ __forceinline__ unsigned short f2bf(float x) {
    unsigned int u = __builtin_bit_cast(unsigned int, x);
    u += 0x7FFFu + ((u >> 16) & 1u);
    return (unsigned short)(u >> 16);
}
static __device__ __forceinline__ float bf2f(unsigned short h) {
    return __builtin_bit_cast(float, (unsigned int)h << 16);
}

// ---- features f32 -> bf16 (streaming; nt loads keep caches for fbf) ----
__global__ void fconv_kernel(const float* __restrict__ f,
                             unsigned short* __restrict__ fb) {
    int i = blockIdx.x * blockDim.x + threadIdx.x;
    const f32x4* src = (const f32x4*)(f + (size_t)i * 8);
    f32x4 a = __builtin_nontemporal_load(src);
    f32x4 b = __builtin_nontemporal_load(src + 1);
    ushort8 h;
    h[0]=f2bf(a[0]); h[1]=f2bf(a[1]); h[2]=f2bf(a[2]); h[3]=f2bf(a[3]);
    h[4]=f2bf(b[0]); h[5]=f2bf(b[1]); h[6]=f2bf(b[2]); h[7]=f2bf(b[3]);
    ((ushort8*)fb)[i] = h;
}

// ---- weight f32 -> bf16, fragment-major: [kt(8)][mblk(16)][ks(2)][lane(64)][8] ----
__global__ void wpack_kernel(const float* __restrict__ w,
                             unsigned short* __restrict__ wp) {
    int c    = blockIdx.x * blockDim.x + threadIdx.x;  // 16384 chunks
    int lane = c & 63;
    int ks   = (c >> 6) & 1;
    int mblk = (c >> 7) & 15;
    int kt   = c >> 11;
    int row  = mblk * 16 + (lane & 15);
    int col  = kt * 64 + ks * 32 + (lane >> 4) * 8;
    const f32x4* src = (const f32x4*)(w + row * K2 + col);
    f32x4 a = src[0], b = src[1];
    ushort8 h;
    h[0]=f2bf(a[0]); h[1]=f2bf(a[1]); h[2]=f2bf(a[2]); h[3]=f2bf(a[3]);
    h[4]=f2bf(b[0]); h[5]=f2bf(b[1]); h[6]=f2bf(b[2]); h[7]=f2bf(b[3]);
    ((ushort8*)wp)[c] = h;
}

// ---- fused gather into 32KB LDS, one barrier, MFMA, relu ----
// occupancy lever: VGPR<=64 fits 8 waves/SIMD -> 4 blocks/CU (128KB LDS, 2048 thr)
template <bool BF16F>
__global__ __launch_bounds__(512, 8) void gemm_fused(
    const float* __restrict__ features,
    const unsigned short* __restrict__ fbf,
    const unsigned short* __restrict__ wp,
    const int* __restrict__ nodes,
    const int* __restrict__ neigh,
    float* __restrict__ out) {

    __shared__ __align__(16) unsigned short lB[BN * K2];   // 32 KB

    const int tid = threadIdx.x;
    const int nb0 = blockIdx.x * BN;

    const int r  = tid >> 4;     // 0..31 batch row in tile
    const int h  = tid & 15;     // 0..15 16-col span
    const int rx = r & 7;
    const int n  = nb0 + r;
    const bool valid = n < BATCH;

    int node0 = valid ? nodes[n] : 0;
    int nidx[NS];
    #pragma unroll
    for (int s = 0; s < NS; ++s) nidx[s] = valid ? neigh[n * NS + s] : 0;

    if (BF16F) {
        ushort8 sa, sb, na[NS], nb[NS];
        {
            const ushort8* sp = (const ushort8*)(fbf + node0 * FEAT + h * 16);
            sa = sp[0];
            sb = sp[1];
        }
        #pragma unroll
        for (int s = 0; s < NS; ++s) {
            const ushort8* p = (const ushort8*)(fbf + nidx[s] * FEAT + h * 16);
            na[s] = p[0];
            nb[s] = p[1];
        }
        __builtin_amdgcn_sched_barrier(0);

        // self half -> LDS
        {
            if (!valid) { ushort8 z = {0,0,0,0,0,0,0,0}; sa = z; sb = z; }
            const int g = h >> 2, i0 = (h & 3) * 2;
            unsigned short* dst = lB + r * K2 + g * 64;
            *(ushort8*)&dst[((i0    ) ^ rx) * 8] = sa;
            *(ushort8*)&dst[((i0 + 1) ^ rx) * 8] = sb;
        }
        // neighbor mean -> LDS
        {
            f32x4 acc0 = {}, acc1 = {}, acc2 = {}, acc3 = {};
            #pragma unroll
            for (int s = 0; s < NS; ++s) {
                #pragma unroll
                for (int e = 0; e < 4; ++e) {
                    acc0[e] += bf2f(na[s][e]);
                    acc1[e] += bf2f(na[s][4 + e]);
                }
            }
            #pragma unroll
            for (int s = 0; s < NS; ++s) {
                #pragma unroll
                for (int e = 0; e < 4; ++e) {
                    acc2[e] += bf2f(nb[s][e]);
                    acc3[e] += bf2f(nb[s][4 + e]);
                }
            }
            ushort8 a, b;
            #pragma unroll
            for (int e = 0; e < 4; ++e) {
                a[e]     = f2bf(valid ? acc0[e] * 0.1f : 0.f);
                a[4 + e] = f2bf(valid ? acc1[e] * 0.1f : 0.f);
                b[e]     = f2bf(valid ? acc2[e] * 0.1f : 0.f);
                b[4 + e] = f2bf(valid ? acc3[e] * 0.1f : 0.f);
            }
            const int g = 4 + (h >> 2), i0 = (h & 3) * 2;
            unsigned short* dst = lB + r * K2 + g * 64;
            *(ushort8*)&dst[((i0    ) ^ rx) * 8] = a;
            *(ushort8*)&dst[((i0 + 1) ^ rx) * 8] = b;
        }
    } else {
        // f32 fallback (ws too small)
        ushort8 a = {0,0,0,0,0,0,0,0}, b = a;
        if (valid) {
            const f32x4* s0 = (const f32x4*)(features + (size_t)node0 * FEAT + h * 16);
            f32x4 x0 = s0[0], x1 = s0[1], x2 = s0[2], x3 = s0[3];
            a[0]=f2bf(x0[0]); a[1]=f2bf(x0[1]); a[2]=f2bf(x0[2]); a[3]=f2bf(x0[3]);
            a[4]=f2bf(x1[0]); a[5]=f2bf(x1[1]); a[6]=f2bf(x1[2]); a[7]=f2bf(x1[3]);
            b[0]=f2bf(x2[0]); b[1]=f2bf(x2[1]); b[2]=f2bf(x2[2]); b[3]=f2bf(x2[3]);
            b[4]=f2bf(x3[0]); b[5]=f2bf(x3[1]); b[6]=f2bf(x3[2]); b[7]=f2bf(x3[3]);
        }
        {
            const int g = h >> 2, i0 = (h & 3) * 2;
            unsigned short* dst = lB + r * K2 + g * 64;
            *(ushort8*)&dst[((i0    ) ^ rx) * 8] = a;
            *(ushort8*)&dst[((i0 + 1) ^ rx) * 8] = b;
        }
        {
            float acc[16];
            #pragma unroll
            for (int e = 0; e < 16; ++e) acc[e] = 0.f;
            #pragma unroll
            for (int s = 0; s < NS; ++s) {
                const f32x4* p = (const f32x4*)(features + (size_t)nidx[s] * FEAT + h * 16);
                f32x4 x0 = p[0], x1 = p[1], x2 = p[2], x3 = p[3];
                #pragma unroll
                for (int e = 0; e < 4; ++e) {
                    acc[e]      += x0[e];
                    acc[4 + e]  += x1[e];
                    acc[8 + e]  += x2[e];
                    acc[12 + e] += x3[e];
                }
            }
            ushort8 aa, bb;
            #pragma unroll
            for (int e = 0; e < 8; ++e) {
                aa[e] = f2bf(valid ? acc[e]     * 0.1f : 0.f);
                bb[e] = f2bf(valid ? acc[8 + e] * 0.1f : 0.f);
            }
            const int g = 4 + (h >> 2), i0 = (h & 3) * 2;
            unsigned short* dst = lB + r * K2 + g * 64;
            *(ushort8*)&dst[((i0    ) ^ rx) * 8] = aa;
            *(ushort8*)&dst[((i0 + 1) ^ rx) * 8] = bb;
        }
    }
    __syncthreads();

    // ---- MFMA phase: 8 waves, wave w -> m rows [w*32, w*32+32), all 32 n-cols ----
    const int w    = tid >> 6;
    const int lane = tid & 63;
    const int lr   = lane & 15;
    const int lg   = lane >> 4;

    f32x4 acc[2][2] = {};

    #pragma unroll
    for (int kt = 0; kt < 8; ++kt) {
        bf16x8 af[2][2], bfr[2][2];
        #pragma unroll
        for (int i = 0; i < 2; ++i)
            #pragma unroll
            for (int ks = 0; ks < 2; ++ks)
                af[i][ks] = *(const bf16x8*)(wp +
                    ((((kt * 16 + w * 2 + i) * 2 + ks) * 64 + lane) << 3));
        #pragma unroll
        for (int j = 0; j < 2; ++j) {
            const int rb = j * 16 + lr;
            #pragma unroll
            for (int ks = 0; ks < 2; ++ks) {
                int ch = kt * 8 + ((ks * 4 + lg) ^ (rb & 7));
                bfr[j][ks] = *(const bf16x8*)&lB[rb * K2 + ch * 8];
            }
        }
        #pragma unroll
        for (int ks = 0; ks < 2; ++ks)
            #pragma unroll
            for (int i = 0; i < 2; ++i)
                #pragma unroll
                for (int j = 0; j < 2; ++j)
                    acc[i][j] = __builtin_amdgcn_mfma_f32_16x16x32_bf16(
                        af[i][ks], bfr[j][ks], acc[i][j], 0, 0, 0);
    }

    // ---- epilogue: relu + nontemporal store. C/D: col=lane&15, row=(lane>>4)*4+reg ----
    #pragma unroll
    for (int j = 0; j < 2; ++j) {
        const int n2 = nb0 + j * 16 + lr;
        if (n2 < BATCH) {
            #pragma unroll
            for (int i = 0; i < 2; ++i) {
                int m0 = w * 32 + i * 16 + lg * 4;
                #pragma unroll
                for (int rg = 0; rg < 4; ++rg) {
                    float v = acc[i][j][rg];
                    v = v > 0.f ? v : 0.f;
                    __builtin_nontemporal_store(v, &out[(size_t)(m0 + rg) * BATCH + n2]);
                }
            }
        }
    }
}

extern "C" void kernel_launch(void* const* d_in, const int* in_sizes, int n_in,
                              void* d_out, int out_size, void* d_ws, size_t ws_size,
                              hipStream_t stream) {
    const float* features = (const float*)d_in[0];
    const float* weight   = (const float*)d_in[1];
    const int*   nodes    = (const int*)d_in[2];
    const int*   neigh    = (const int*)d_in[3];
    float* out = (float*)d_out;

    unsigned short* wp  = (unsigned short*)d_ws;              // 256 KB packed weight
    unsigned short* fbf = wp + (size_t)EMBED * K2;            // 51.2 MB bf16 features

    const size_t need = (size_t)EMBED * K2 * 2 + (size_t)NNODES * FEAT * 2;

    wpack_kernel<<<(EMBED * K2 / 8) / 256, 256, 0, stream>>>(weight, wp);

    if (ws_size >= need) {
        fconv_kernel<<<(NNODES * FEAT / 8) / 256, 256, 0, stream>>>(features, fbf);
        gemm_fused<true><<<NBLK, 512, 0, stream>>>(features, fbf, wp, nodes, neigh, out);
    } else {
        gemm_fused<false><<<NBLK, 512, 0, stream>>>(features, fbf, wp, nodes, neigh, out);
    }
}

// Round 7
// 94.893 us; speedup vs baseline: 1.4877x; 1.4877x over previous
//
#include <hip/hip_runtime.h>

#define FEAT   256
#define K2     512      // 2*FEAT
#define NNODES 100000
#define BATCH  50000
#define NS     10
#define EMBED  256
#define BN     32
#define NBLK   ((BATCH + BN - 1) / BN)   // 1563

typedef __attribute__((ext_vector_type(8))) __bf16         bf16x8;
typedef __attribute__((ext_vector_type(8))) unsigned short ushort8;
typedef __attribute__((ext_vector_type(4))) float          f32x4;

static __device__ __forceinline__ unsigned short f2bf(float x) {
    unsigned int u = __builtin_bit_cast(unsigned int, x);
    u += 0x7FFFu + ((u >> 16) & 1u);
    return (unsigned short)(u >> 16);
}
static __device__ __forceinline__ float bf2f(unsigned short h) {
    return __builtin_bit_cast(float, (unsigned int)h << 16);
}
// async global->LDS DMA, 16B per lane, dest = wave-uniform base + lane*16
static __device__ __forceinline__ void gload16(void* lds, const void* g) {
    __builtin_amdgcn_global_load_lds(
        (const __attribute__((address_space(1))) void*)g,
        (__attribute__((address_space(3))) void*)lds, 16, 0, 0);
}

// ---- features f32 -> bf16 (streaming; nt loads keep caches for fbf) ----
__global__ void fconv_kernel(const float* __restrict__ f,
                             unsigned short* __restrict__ fb) {
    int i = blockIdx.x * blockDim.x + threadIdx.x;
    const f32x4* src = (const f32x4*)(f + (size_t)i * 8);
    f32x4 a = __builtin_nontemporal_load(src);
    f32x4 b = __builtin_nontemporal_load(src + 1);
    ushort8 h;
    h[0]=f2bf(a[0]); h[1]=f2bf(a[1]); h[2]=f2bf(a[2]); h[3]=f2bf(a[3]);
    h[4]=f2bf(b[0]); h[5]=f2bf(b[1]); h[6]=f2bf(b[2]); h[7]=f2bf(b[3]);
    ((ushort8*)fb)[i] = h;
}

// ---- weight f32 -> bf16, fragment-major: [kt(8)][mblk(16)][ks(2)][lane(64)][8] ----
__global__ void wpack_kernel(const float* __restrict__ w,
                             unsigned short* __restrict__ wp) {
    int c    = blockIdx.x * blockDim.x + threadIdx.x;  // 16384 chunks
    int lane = c & 63;
    int ks   = (c >> 6) & 1;
    int mblk = (c >> 7) & 15;
    int kt   = c >> 11;
    int row  = mblk * 16 + (lane & 15);
    int col  = kt * 64 + ks * 32 + (lane >> 4) * 8;
    const f32x4* src = (const f32x4*)(w + row * K2 + col);
    f32x4 a = src[0], b = src[1];
    ushort8 h;
    h[0]=f2bf(a[0]); h[1]=f2bf(a[1]); h[2]=f2bf(a[2]); h[3]=f2bf(a[3]);
    h[4]=f2bf(b[0]); h[5]=f2bf(b[1]); h[6]=f2bf(b[2]); h[7]=f2bf(b[3]);
    ((ushort8*)wp)[c] = h;
}

// ---- bf16 path: async-DMA staged gather (3-deep counted-vmcnt pipeline) + MFMA ----
// LDS: lB = final combined tile [32 rows][512 cols] bf16, XOR-swizzled chunks;
//      stg[3] = neighbor staging [32 rows][256 cols] bf16, linear.
// Per wave (8 waves): DMA owns batch-rows 4w..4w+3. Self rows -> lB directly
// (pre-swizzled global source); neighbor set s -> stg[s%3], issued 3 ahead.
__global__ __launch_bounds__(512, 4) void gemm_dma(
    const unsigned short* __restrict__ fbf,
    const unsigned short* __restrict__ wp,
    const int* __restrict__ nodes,
    const int* __restrict__ neigh,
    float* __restrict__ out) {

    __shared__ __align__(16) unsigned short lB[BN * K2];        // 32 KB
    __shared__ __align__(16) unsigned short stg[3][BN * FEAT];  // 48 KB

    const int tid  = threadIdx.x;
    const int nb0  = blockIdx.x * BN;
    const int w    = tid >> 6;
    const int lane = tid & 63;
    const char* fb = (const char*)fbf;

    // ---- per-lane index preload (byte offsets, oldest vmem ops) ----
    const int rl  = 4 * w + (lane >> 5);           // row for instr p=2w
    const int n_l = min(nb0 + rl, BATCH - 1);
    const int n_h = min(nb0 + rl + 2, BATCH - 1);  // row for instr p=2w+1
    int off_s[4];
    #pragma unroll
    for (int j = 0; j < 4; ++j)
        off_s[j] = nodes[min(nb0 + 4 * w + j, BATCH - 1)] << 9;
    int on_l[NS], on_h[NS];
    #pragma unroll
    for (int s = 0; s < NS; ++s) {
        on_l[s] = neigh[n_l * NS + s] << 9;
        on_h[s] = neigh[n_h * NS + s] << 9;
    }
    asm volatile("s_waitcnt vmcnt(0)" ::: "memory");

    // ---- self DMA into lB (half-exec, source pre-swizzled: chunk low3 ^= row&7) ----
    #pragma unroll
    for (int j = 0; j < 4; ++j) {
        const int r = 4 * w + j, rx = r & 7;
        if (lane < 32) {
            const int cs = (lane & ~7) | ((lane & 7) ^ rx);
            gload16(&lB[r * K2], fb + off_s[j] + cs * 16);
        }
    }
    // ---- pre-issue neighbor phases 0..2 ----
    #pragma unroll
    for (int s = 0; s < 3; ++s) {
        gload16(&stg[s][(2 * w)     * 512], fb + on_l[s] + (lane & 31) * 16);
        gload16(&stg[s][(2 * w + 1) * 512], fb + on_h[s] + (lane & 31) * 16);
    }

    // ---- pipelined consume: wait(counted) -> barrier -> accumulate -> barrier -> reissue ----
    const int cr  = tid >> 4;     // 0..31 row
    const int ch  = tid & 15;     // 0..15 16-col span
    const int crx = cr & 7;
    float acc[16];
    #pragma unroll
    for (int e = 0; e < 16; ++e) acc[e] = 0.f;

    #pragma unroll
    for (int s = 0; s < NS; ++s) {
        if (s <= 7)      asm volatile("s_waitcnt vmcnt(4)" ::: "memory");
        else if (s == 8) asm volatile("s_waitcnt vmcnt(2)" ::: "memory");
        else             asm volatile("s_waitcnt vmcnt(0)" ::: "memory");
        __builtin_amdgcn_s_barrier();          // all waves' phase-s DMAs landed
        __builtin_amdgcn_sched_barrier(0);

        const ushort8* p8 = (const ushort8*)&stg[s % 3][cr * 256 + ch * 16];
        ushort8 va = p8[0], vb = p8[1];
        #pragma unroll
        for (int e = 0; e < 8; ++e) {
            acc[e]     += bf2f(va[e]);
            acc[8 + e] += bf2f(vb[e]);
        }
        __builtin_amdgcn_sched_barrier(0);
        __builtin_amdgcn_s_barrier();          // all reads of stg[s%3] done
        __builtin_amdgcn_sched_barrier(0);
        if (s + 3 < NS) {                      // reissue same buffer for phase s+3
            gload16(&stg[s % 3][(2 * w)     * 512], fb + on_l[s + 3] + (lane & 31) * 16);
            gload16(&stg[s % 3][(2 * w + 1) * 512], fb + on_h[s + 3] + (lane & 31) * 16);
        }
    }

    // ---- mean -> bf16 -> lB (swizzled chunks) ----
    {
        ushort8 a, b;
        #pragma unroll
        for (int e = 0; e < 8; ++e) {
            a[e] = f2bf(acc[e] * 0.1f);
            b[e] = f2bf(acc[8 + e] * 0.1f);
        }
        const int g = 4 + (ch >> 2), i0 = (ch & 3) * 2;
        unsigned short* dst = lB + cr * K2 + g * 64;
        *(ushort8*)&dst[((i0    ) ^ crx) * 8] = a;
        *(ushort8*)&dst[((i0 + 1) ^ crx) * 8] = b;
    }
    __syncthreads();   // full drain OK here (vmcnt already 0)

    // ---- MFMA: 8 waves, wave w -> m rows [w*32, w*32+32), all 32 n-cols ----
    const int lr = lane & 15;
    const int lg = lane >> 4;

    f32x4 facc[2][2] = {};

    #pragma unroll
    for (int kt = 0; kt < 8; ++kt) {
        bf16x8 af[2][2], bfr[2][2];
        #pragma unroll
        for (int i = 0; i < 2; ++i)
            #pragma unroll
            for (int ks = 0; ks < 2; ++ks)
                af[i][ks] = *(const bf16x8*)(wp +
                    ((((kt * 16 + w * 2 + i) * 2 + ks) * 64 + lane) << 3));
        #pragma unroll
        for (int j = 0; j < 2; ++j) {
            const int rb = j * 16 + lr;
            #pragma unroll
            for (int ks = 0; ks < 2; ++ks) {
                int cc = kt * 8 + ((ks * 4 + lg) ^ (rb & 7));
                bfr[j][ks] = *(const bf16x8*)&lB[rb * K2 + cc * 8];
            }
        }
        #pragma unroll
        for (int ks = 0; ks < 2; ++ks)
            #pragma unroll
            for (int i = 0; i < 2; ++i)
                #pragma unroll
                for (int j = 0; j < 2; ++j)
                    facc[i][j] = __builtin_amdgcn_mfma_f32_16x16x32_bf16(
                        af[i][ks], bfr[j][ks], facc[i][j], 0, 0, 0);
    }

    // ---- epilogue: relu + nt store. C/D: col=lane&15, row=(lane>>4)*4+reg ----
    #pragma unroll
    for (int j = 0; j < 2; ++j) {
        const int n2 = nb0 + j * 16 + lr;
        if (n2 < BATCH) {
            #pragma unroll
            for (int i = 0; i < 2; ++i) {
                int m0 = w * 32 + i * 16 + lg * 4;
                #pragma unroll
                for (int rg = 0; rg < 4; ++rg) {
                    float v = facc[i][j][rg];
                    v = v > 0.f ? v : 0.f;
                    __builtin_nontemporal_store(v, &out[(size_t)(m0 + rg) * BATCH + n2]);
                }
            }
        }
    }
}

// ---- f32 fallback (ws too small): R5 register-gather version ----
__global__ __launch_bounds__(512, 4) void gemm_f32(
    const float* __restrict__ features,
    const unsigned short* __restrict__ wp,
    const int* __restrict__ nodes,
    const int* __restrict__ neigh,
    float* __restrict__ out) {

    __shared__ __align__(16) unsigned short lB[BN * K2];

    const int tid = threadIdx.x;
    const int nb0 = blockIdx.x * BN;
    const int r  = tid >> 4;
    const int h  = tid & 15;
    const int rx = r & 7;
    const int n  = nb0 + r;
    const bool valid = n < BATCH;

    int node0 = valid ? nodes[n] : 0;
    int nidx[NS];
    #pragma unroll
    for (int s = 0; s < NS; ++s) nidx[s] = valid ? neigh[n * NS + s] : 0;

    ushort8 a = {0,0,0,0,0,0,0,0}, b = a;
    if (valid) {
        const f32x4* s0 = (const f32x4*)(features + (size_t)node0 * FEAT + h * 16);
        f32x4 x0 = s0[0], x1 = s0[1], x2 = s0[2], x3 = s0[3];
        a[0]=f2bf(x0[0]); a[1]=f2bf(x0[1]); a[2]=f2bf(x0[2]); a[3]=f2bf(x0[3]);
        a[4]=f2bf(x1[0]); a[5]=f2bf(x1[1]); a[6]=f2bf(x1[2]); a[7]=f2bf(x1[3]);
        b[0]=f2bf(x2[0]); b[1]=f2bf(x2[1]); b[2]=f2bf(x2[2]); b[3]=f2bf(x2[3]);
        b[4]=f2bf(x3[0]); b[5]=f2bf(x3[1]); b[6]=f2bf(x3[2]); b[7]=f2bf(x3[3]);
    }
    {
        const int g = h >> 2, i0 = (h & 3) * 2;
        unsigned short* dst = lB + r * K2 + g * 64;
        *(ushort8*)&dst[((i0    ) ^ rx) * 8] = a;
        *(ushort8*)&dst[((i0 + 1) ^ rx) * 8] = b;
    }
    {
        float acc[16];
        #pragma unroll
        for (int e = 0; e < 16; ++e) acc[e] = 0.f;
        #pragma unroll
        for (int s = 0; s < NS; ++s) {
            const f32x4* p = (const f32x4*)(features + (size_t)nidx[s] * FEAT + h * 16);
            f32x4 x0 = p[0], x1 = p[1], x2 = p[2], x3 = p[3];
            #pragma unroll
            for (int e = 0; e < 4; ++e) {
                acc[e]      += x0[e];
                acc[4 + e]  += x1[e];
                acc[8 + e]  += x2[e];
                acc[12 + e] += x3[e];
            }
        }
        ushort8 aa, bb;
        #pragma unroll
        for (int e = 0; e < 8; ++e) {
            aa[e] = f2bf(valid ? acc[e]     * 0.1f : 0.f);
            bb[e] = f2bf(valid ? acc[8 + e] * 0.1f : 0.f);
        }
        const int g = 4 + (h >> 2), i0 = (h & 3) * 2;
        unsigned short* dst = lB + r * K2 + g * 64;
        *(ushort8*)&dst[((i0    ) ^ rx) * 8] = aa;
        *(ushort8*)&dst[((i0 + 1) ^ rx) * 8] = bb;
    }
    __syncthreads();

    const int w    = tid >> 6;
    const int lane = tid & 63;
    const int lr   = lane & 15;
    const int lg   = lane >> 4;

    f32x4 facc[2][2] = {};
    #pragma unroll
    for (int kt = 0; kt < 8; ++kt) {
        bf16x8 af[2][2], bfr[2][2];
        #pragma unroll
        for (int i = 0; i < 2; ++i)
            #pragma unroll
            for (int ks = 0; ks < 2; ++ks)
                af[i][ks] = *(const bf16x8*)(wp +
                    ((((kt * 16 + w * 2 + i) * 2 + ks) * 64 + lane) << 3));
        #pragma unroll
        for (int j = 0; j < 2; ++j) {
            const int rb = j * 16 + lr;
            #pragma unroll
            for (int ks = 0; ks < 2; ++ks) {
                int cc = kt * 8 + ((ks * 4 + lg) ^ (rb & 7));
                bfr[j][ks] = *(const bf16x8*)&lB[rb * K2 + cc * 8];
            }
        }
        #pragma unroll
        for (int ks = 0; ks < 2; ++ks)
            #pragma unroll
            for (int i = 0; i < 2; ++i)
                #pragma unroll
                for (int j = 0; j < 2; ++j)
                    facc[i][j] = __builtin_amdgcn_mfma_f32_16x16x32_bf16(
                        af[i][ks], bfr[j][ks], facc[i][j], 0, 0, 0);
    }
    #pragma unroll
    for (int j = 0; j < 2; ++j) {
        const int n2 = nb0 + j * 16 + lr;
        if (n2 < BATCH) {
            #pragma unroll
            for (int i = 0; i < 2; ++i) {
                int m0 = w * 32 + i * 16 + lg * 4;
                #pragma unroll
                for (int rg = 0; rg < 4; ++rg) {
                    float v = facc[i][j][rg];
                    v = v > 0.f ? v : 0.f;
                    __builtin_nontemporal_store(v, &out[(size_t)(m0 + rg) * BATCH + n2]);
                }
            }
        }
    }
}

extern "C" void kernel_launch(void* const* d_in, const int* in_sizes, int n_in,
                              void* d_out, int out_size, void* d_ws, size_t ws_size,
                              hipStream_t stream) {
    const float* features = (const float*)d_in[0];
    const float* weight   = (const float*)d_in[1];
    const int*   nodes    = (const int*)d_in[2];
    const int*   neigh    = (const int*)d_in[3];
    float* out = (float*)d_out;

    unsigned short* wp  = (unsigned short*)d_ws;              // 256 KB packed weight
    unsigned short* fbf = wp + (size_t)EMBED * K2;            // 51.2 MB bf16 features

    const size_t need = (size_t)EMBED * K2 * 2 + (size_t)NNODES * FEAT * 2;

    wpack_kernel<<<(EMBED * K2 / 8) / 256, 256, 0, stream>>>(weight, wp);

    if (ws_size >= need) {
        fconv_kernel<<<(NNODES * FEAT / 8) / 256, 256, 0, stream>>>(features, fbf);
        gemm_dma<<<NBLK, 512, 0, stream>>>(fbf, wp, nodes, neigh, out);
    } else {
        gemm_f32<<<NBLK, 512, 0, stream>>>(features, wp, nodes, neigh, out);
    }
}

// Round 8
// 85.469 us; speedup vs baseline: 1.6517x; 1.1103x over previous
//
#include <hip/hip_runtime.h>

#define FEAT   256
#define K2     512      // 2*FEAT
#define NNODES 100000
#define BATCH  50000
#define NS     10
#define EMBED  256
#define BN     32
#define NBLK   ((BATCH + BN - 1) / BN)   // 1563

typedef __attribute__((ext_vector_type(8))) __bf16         bf16x8;
typedef __attribute__((ext_vector_type(8))) unsigned short ushort8;
typedef __attribute__((ext_vector_type(4))) float          f32x4;
typedef __attribute__((ext_vector_type(2))) float          f32x2;
typedef __attribute__((ext_vector_type(2))) int            i32x2;
typedef __attribute__((ext_vector_type(4))) int            i32x4;

static __device__ __forceinline__ unsigned short f2bf(float x) {
    unsigned int u = __builtin_bit_cast(unsigned int, x);
    u += 0x7FFFu + ((u >> 16) & 1u);
    return (unsigned short)(u >> 16);
}
static __device__ __forceinline__ float bf2f(unsigned short h) {
    return __builtin_bit_cast(float, (unsigned int)h << 16);
}
// async global->LDS DMA, 16B per lane, dest = wave-uniform base + lane*16
static __device__ __forceinline__ void gload16(void* lds, const void* g) {
    __builtin_amdgcn_global_load_lds(
        (const __attribute__((address_space(1))) void*)g,
        (__attribute__((address_space(3))) void*)lds, 16, 0, 0);
}

// ---- features f32 -> bf16 table (self) + fp8 e4m3 table (neighbors) ----
__global__ void fconv_kernel(const float* __restrict__ f,
                             unsigned short* __restrict__ fb,
                             unsigned char* __restrict__ f8) {
    int i = blockIdx.x * blockDim.x + threadIdx.x;   // one 8-elem chunk
    const f32x4* src = (const f32x4*)(f + (size_t)i * 8);
    f32x4 a = __builtin_nontemporal_load(src);
    f32x4 b = __builtin_nontemporal_load(src + 1);
    ushort8 h;
    h[0]=f2bf(a[0]); h[1]=f2bf(a[1]); h[2]=f2bf(a[2]); h[3]=f2bf(a[3]);
    h[4]=f2bf(b[0]); h[5]=f2bf(b[1]); h[6]=f2bf(b[2]); h[7]=f2bf(b[3]);
    ((ushort8*)fb)[i] = h;
    int u0 = 0, u1 = 0;
    u0 = __builtin_amdgcn_cvt_pk_fp8_f32(a[0], a[1], u0, false);
    u0 = __builtin_amdgcn_cvt_pk_fp8_f32(a[2], a[3], u0, true);
    u1 = __builtin_amdgcn_cvt_pk_fp8_f32(b[0], b[1], u1, false);
    u1 = __builtin_amdgcn_cvt_pk_fp8_f32(b[2], b[3], u1, true);
    i32x2 p; p[0] = u0; p[1] = u1;
    ((i32x2*)f8)[i] = p;
}

// ---- weight f32 -> bf16, fragment-major: [kt(8)][mblk(16)][ks(2)][lane(64)][8] ----
__global__ void wpack_kernel(const float* __restrict__ w,
                             unsigned short* __restrict__ wp) {
    int c    = blockIdx.x * blockDim.x + threadIdx.x;  // 16384 chunks
    int lane = c & 63;
    int ks   = (c >> 6) & 1;
    int mblk = (c >> 7) & 15;
    int kt   = c >> 11;
    int row  = mblk * 16 + (lane & 15);
    int col  = kt * 64 + ks * 32 + (lane >> 4) * 8;
    const f32x4* src = (const f32x4*)(w + row * K2 + col);
    f32x4 a = src[0], b = src[1];
    ushort8 h;
    h[0]=f2bf(a[0]); h[1]=f2bf(a[1]); h[2]=f2bf(a[2]); h[3]=f2bf(a[3]);
    h[4]=f2bf(b[0]); h[5]=f2bf(b[1]); h[6]=f2bf(b[2]); h[7]=f2bf(b[3]);
    ((ushort8*)wp)[c] = h;
}

// ---- bf16 self (DMA) + fp8 neighbor (DMA, 3-deep counted-vmcnt) + MFMA ----
// LDS: lB = combined tile [32][512] bf16, XOR-swizzled chunks (16B chunk low3 ^= row&7)
//      s8[3] = neighbor staging [32 rows][256 B] fp8, linear.
__global__ __launch_bounds__(512, 4) void gemm_dma(
    const unsigned short* __restrict__ fbf,
    const unsigned char* __restrict__ ffp8,
    const unsigned short* __restrict__ wp,
    const int* __restrict__ nodes,
    const int* __restrict__ neigh,
    float* __restrict__ out) {

    __shared__ __align__(16) unsigned short lB[BN * K2];      // 32 KB
    __shared__ __align__(16) unsigned char  s8[3][BN * FEAT]; // 24 KB

    const int tid  = threadIdx.x;
    const int nb0  = blockIdx.x * BN;
    const int w    = tid >> 6;
    const int lane = tid & 63;
    const char* fbb = (const char*)fbf;
    const char* f8b = (const char*)ffp8;

    // ---- per-lane index loads (oldest vmem ops) ----
    // self: row pair for half-exec DMA j=0..3 handled via lane>>5 per instr
    int off_s[4];
    #pragma unroll
    for (int j = 0; j < 4; ++j)
        off_s[j] = nodes[min(nb0 + 4 * w + j, BATCH - 1)] << 9;   // bf16 row = 512 B
    // neighbor: this lane's row for fp8 staging = 4w + (lane>>4)
    const int nrow = min(nb0 + 4 * w + (lane >> 4), BATCH - 1);
    int on[NS];
    #pragma unroll
    for (int s = 0; s < NS; ++s)
        on[s] = neigh[nrow * NS + s] << 8;                        // fp8 row = 256 B
    asm volatile("s_waitcnt vmcnt(0)" ::: "memory");

    // ---- self DMA into lB rows 4w..4w+3 (half-exec, pre-swizzled source) ----
    #pragma unroll
    for (int j = 0; j < 4; ++j) {
        const int r = 4 * w + j, rx = r & 7;
        if (lane < 32) {
            const int c  = lane;                       // 16B chunk 0..31 (cols 0..255)
            const int cs = (c & ~7) | ((c & 7) ^ rx);
            gload16(&lB[r * K2], fbb + off_s[j] + cs * 16);
        }
    }
    // ---- pre-issue neighbor phases 0..2 (1 instr/wave: 4 rows x 256 B) ----
    #pragma unroll
    for (int s = 0; s < 3; ++s)
        gload16(&s8[s][w * 1024], f8b + on[s] + (lane & 15) * 16);

    // ---- pipelined consume ----
    const int cr  = tid >> 4;     // 0..31 row
    const int ch  = tid & 15;     // 0..15 16-col span
    const int crx = cr & 7;
    float acc[16];
    #pragma unroll
    for (int e = 0; e < 16; ++e) acc[e] = 0.f;

    #pragma unroll
    for (int s = 0; s < NS; ++s) {
        if (s <= 7)      asm volatile("s_waitcnt vmcnt(2)" ::: "memory");
        else if (s == 8) asm volatile("s_waitcnt vmcnt(1)" ::: "memory");
        else             asm volatile("s_waitcnt vmcnt(0)" ::: "memory");
        __builtin_amdgcn_s_barrier();          // phase-s staging landed (all waves)
        __builtin_amdgcn_sched_barrier(0);

        i32x4 v = *(const i32x4*)&s8[s % 3][cr * 256 + ch * 16];
        #pragma unroll
        for (int q = 0; q < 4; ++q) {
            f32x2 lo = __builtin_amdgcn_cvt_pk_f32_fp8(v[q], false);
            f32x2 hi = __builtin_amdgcn_cvt_pk_f32_fp8(v[q], true);
            acc[q * 4 + 0] += lo[0];
            acc[q * 4 + 1] += lo[1];
            acc[q * 4 + 2] += hi[0];
            acc[q * 4 + 3] += hi[1];
        }
        __builtin_amdgcn_sched_barrier(0);
        __builtin_amdgcn_s_barrier();          // all reads of s8[s%3] done
        __builtin_amdgcn_sched_barrier(0);
        if (s + 3 < NS)                        // reissue buffer for phase s+3
            gload16(&s8[s % 3][w * 1024], f8b + on[s + 3] + (lane & 15) * 16);
    }

    // ---- mean -> bf16 -> lB neighbor half (groups 4..7, swizzled) ----
    {
        ushort8 a, b;
        #pragma unroll
        for (int e = 0; e < 8; ++e) {
            a[e] = f2bf(acc[e] * 0.1f);
            b[e] = f2bf(acc[8 + e] * 0.1f);
        }
        const int g = 4 + (ch >> 2), i0 = (ch & 3) * 2;
        unsigned short* dst = lB + cr * K2 + g * 64;
        *(ushort8*)&dst[((i0    ) ^ crx) * 8] = a;
        *(ushort8*)&dst[((i0 + 1) ^ crx) * 8] = b;
    }
    __syncthreads();   // vmcnt already 0; all LDS writes visible

    // ---- MFMA: wave w -> m rows [w*32, w*32+32), all 32 n-cols ----
    const int lr = lane & 15;
    const int lg = lane >> 4;

    f32x4 facc[2][2] = {};

    #pragma unroll
    for (int kt = 0; kt < 8; ++kt) {
        bf16x8 af[2][2], bfr[2][2];
        #pragma unroll
        for (int i = 0; i < 2; ++i)
            #pragma unroll
            for (int ks = 0; ks < 2; ++ks)
                af[i][ks] = *(const bf16x8*)(wp +
                    ((((kt * 16 + w * 2 + i) * 2 + ks) * 64 + lane) << 3));
        #pragma unroll
        for (int j = 0; j < 2; ++j) {
            const int rb = j * 16 + lr;
            #pragma unroll
            for (int ks = 0; ks < 2; ++ks) {
                int cc = kt * 8 + ((ks * 4 + lg) ^ (rb & 7));
                bfr[j][ks] = *(const bf16x8*)&lB[rb * K2 + cc * 8];
            }
        }
        #pragma unroll
        for (int ks = 0; ks < 2; ++ks)
            #pragma unroll
            for (int i = 0; i < 2; ++i)
                #pragma unroll
                for (int j = 0; j < 2; ++j)
                    facc[i][j] = __builtin_amdgcn_mfma_f32_16x16x32_bf16(
                        af[i][ks], bfr[j][ks], facc[i][j], 0, 0, 0);
    }

    // ---- epilogue: relu + nt store. C/D: col=lane&15, row=(lane>>4)*4+reg ----
    #pragma unroll
    for (int j = 0; j < 2; ++j) {
        const int n2 = nb0 + j * 16 + lr;
        if (n2 < BATCH) {
            #pragma unroll
            for (int i = 0; i < 2; ++i) {
                int m0 = w * 32 + i * 16 + lg * 4;
                #pragma unroll
                for (int rg = 0; rg < 4; ++rg) {
                    float v = facc[i][j][rg];
                    v = v > 0.f ? v : 0.f;
                    __builtin_nontemporal_store(v, &out[(size_t)(m0 + rg) * BATCH + n2]);
                }
            }
        }
    }
}

// ---- f32 fallback (ws too small) ----
__global__ __launch_bounds__(512, 4) void gemm_f32(
    const float* __restrict__ features,
    const unsigned short* __restrict__ wp,
    const int* __restrict__ nodes,
    const int* __restrict__ neigh,
    float* __restrict__ out) {

    __shared__ __align__(16) unsigned short lB[BN * K2];

    const int tid = threadIdx.x;
    const int nb0 = blockIdx.x * BN;
    const int r  = tid >> 4;
    const int h  = tid & 15;
    const int rx = r & 7;
    const int n  = nb0 + r;
    const bool valid = n < BATCH;

    int node0 = valid ? nodes[n] : 0;
    int nidx[NS];
    #pragma unroll
    for (int s = 0; s < NS; ++s) nidx[s] = valid ? neigh[n * NS + s] : 0;

    ushort8 a = {0,0,0,0,0,0,0,0}, b = a;
    if (valid) {
        const f32x4* s0 = (const f32x4*)(features + (size_t)node0 * FEAT + h * 16);
        f32x4 x0 = s0[0], x1 = s0[1], x2 = s0[2], x3 = s0[3];
        a[0]=f2bf(x0[0]); a[1]=f2bf(x0[1]); a[2]=f2bf(x0[2]); a[3]=f2bf(x0[3]);
        a[4]=f2bf(x1[0]); a[5]=f2bf(x1[1]); a[6]=f2bf(x1[2]); a[7]=f2bf(x1[3]);
        b[0]=f2bf(x2[0]); b[1]=f2bf(x2[1]); b[2]=f2bf(x2[2]); b[3]=f2bf(x2[3]);
        b[4]=f2bf(x3[0]); b[5]=f2bf(x3[1]); b[6]=f2bf(x3[2]); b[7]=f2bf(x3[3]);
    }
    {
        const int g = h >> 2, i0 = (h & 3) * 2;
        unsigned short* dst = lB + r * K2 + g * 64;
        *(ushort8*)&dst[((i0    ) ^ rx) * 8] = a;
        *(ushort8*)&dst[((i0 + 1) ^ rx) * 8] = b;
    }
    {
        float acc[16];
        #pragma unroll
        for (int e = 0; e < 16; ++e) acc[e] = 0.f;
        #pragma unroll
        for (int s = 0; s < NS; ++s) {
            const f32x4* p = (const f32x4*)(features + (size_t)nidx[s] * FEAT + h * 16);
            f32x4 x0 = p[0], x1 = p[1], x2 = p[2], x3 = p[3];
            #pragma unroll
            for (int e = 0; e < 4; ++e) {
                acc[e]      += x0[e];
                acc[4 + e]  += x1[e];
                acc[8 + e]  += x2[e];
                acc[12 + e] += x3[e];
            }
        }
        ushort8 aa, bb;
        #pragma unroll
        for (int e = 0; e < 8; ++e) {
            aa[e] = f2bf(valid ? acc[e]     * 0.1f : 0.f);
            bb[e] = f2bf(valid ? acc[8 + e] * 0.1f : 0.f);
        }
        const int g = 4 + (h >> 2), i0 = (h & 3) * 2;
        unsigned short* dst = lB + r * K2 + g * 64;
        *(ushort8*)&dst[((i0    ) ^ rx) * 8] = aa;
        *(ushort8*)&dst[((i0 + 1) ^ rx) * 8] = bb;
    }
    __syncthreads();

    const int w    = tid >> 6;
    const int lane = tid & 63;
    const int lr   = lane & 15;
    const int lg   = lane >> 4;

    f32x4 facc[2][2] = {};
    #pragma unroll
    for (int kt = 0; kt < 8; ++kt) {
        bf16x8 af[2][2], bfr[2][2];
        #pragma unroll
        for (int i = 0; i < 2; ++i)
            #pragma unroll
            for (int ks = 0; ks < 2; ++ks)
                af[i][ks] = *(const bf16x8*)(wp +
                    ((((kt * 16 + w * 2 + i) * 2 + ks) * 64 + lane) << 3));
        #pragma unroll
        for (int j = 0; j < 2; ++j) {
            const int rb = j * 16 + lr;
            #pragma unroll
            for (int ks = 0; ks < 2; ++ks) {
                int cc = kt * 8 + ((ks * 4 + lg) ^ (rb & 7));
                bfr[j][ks] = *(const bf16x8*)&lB[rb * K2 + cc * 8];
            }
        }
        #pragma unroll
        for (int ks = 0; ks < 2; ++ks)
            #pragma unroll
            for (int i = 0; i < 2; ++i)
                #pragma unroll
                for (int j = 0; j < 2; ++j)
                    facc[i][j] = __builtin_amdgcn_mfma_f32_16x16x32_bf16(
                        af[i][ks], bfr[j][ks], facc[i][j], 0, 0, 0);
    }
    #pragma unroll
    for (int j = 0; j < 2; ++j) {
        const int n2 = nb0 + j * 16 + lr;
        if (n2 < BATCH) {
            #pragma unroll
            for (int i = 0; i < 2; ++i) {
                int m0 = w * 32 + i * 16 + lg * 4;
                #pragma unroll
                for (int rg = 0; rg < 4; ++rg) {
                    float v = facc[i][j][rg];
                    v = v > 0.f ? v : 0.f;
                    __builtin_nontemporal_store(v, &out[(size_t)(m0 + rg) * BATCH + n2]);
                }
            }
        }
    }
}

extern "C" void kernel_launch(void* const* d_in, const int* in_sizes, int n_in,
                              void* d_out, int out_size, void* d_ws, size_t ws_size,
                              hipStream_t stream) {
    const float* features = (const float*)d_in[0];
    const float* weight   = (const float*)d_in[1];
    const int*   nodes    = (const int*)d_in[2];
    const int*   neigh    = (const int*)d_in[3];
    float* out = (float*)d_out;

    unsigned short* wp   = (unsigned short*)d_ws;             // 256 KB packed weight
    unsigned short* fbf  = wp + (size_t)EMBED * K2;           // 51.2 MB bf16 features
    unsigned char*  ffp8 = (unsigned char*)(fbf + (size_t)NNODES * FEAT); // 25.6 MB fp8

    const size_t need = (size_t)EMBED * K2 * 2 + (size_t)NNODES * FEAT * 3;

    wpack_kernel<<<(EMBED * K2 / 8) / 256, 256, 0, stream>>>(weight, wp);

    if (ws_size >= need) {
        fconv_kernel<<<(NNODES * FEAT / 8) / 256, 256, 0, stream>>>(features, fbf, ffp8);
        gemm_dma<<<NBLK, 512, 0, stream>>>(fbf, ffp8, wp, nodes, neigh, out);
    } else {
        gemm_f32<<<NBLK, 512, 0, stream>>>(features, wp, nodes, neigh, out);
    }
}